// Round 5
// baseline (114.736 us; speedup 1.0000x reference)
//
#include <hip/hip_runtime.h>
#include <hip/hip_bf16.h>

#define B_ 4
#define S_ 512
#define E_ 512
#define U_ 256

// 2*log2(e): folded so tanh args feed exp2 directly: exp(2x) = exp2(KC*x)
#define KC 2.885390081777927f

#if __has_builtin(__builtin_amdgcn_exp2f)
#define EXP2F(x) __builtin_amdgcn_exp2f(x)
#else
#define EXP2F(x) __exp2f(x)
#endif
#if __has_builtin(__builtin_amdgcn_rcpf)
#define RCPF(x) __builtin_amdgcn_rcpf(x)
#else
#define RCPF(x) (1.0f / (x))
#endif

typedef __attribute__((ext_vector_type(8))) short bf16x8;
typedef __attribute__((ext_vector_type(4))) float f32x4;

__device__ __forceinline__ unsigned short bf16rn(float x) {
    unsigned int u = __float_as_uint(x);
    u = (u + 0x7FFFu + ((u >> 16) & 1u)) >> 16;   // RNE
    return (unsigned short)u;
}
// truncation split: x = hi + lo (lo exact in fp32); dropped lo*lo term ~2^-16
__device__ __forceinline__ void splitT(float x, short* hi, short* lo) {
    const unsigned u = __float_as_uint(x);
    *hi = (short)(u >> 16);
    const float hf = __uint_as_float(u & 0xFFFF0000u);
    *lo = (short)(__float_as_uint(x - hf) >> 16);
}

// ---------------------------------------------------------------------------
// convert: one memory-bound pass producing ALL bf16 fragments.
//  blocks    0..1023 -> Af : hi/lo A-frags of h1 (z=0), h2 (z=1), KC-scaled.
//                           layout [z*256 + mt][kc][lane], lo at +128*16*64.
//  blocks 1024..1535 -> h1c: bf16 B-frags of h1 (k = S dim) for pv.
//  blocks 1536..1663 -> Wf : hi/lo B-frags of W for prep (slab ng16 = u/16).
//                           layout [(z*16+ng16)*16+kc][lane], lo at +32768.
//  (Wf is what prep previously re-built in LDS per block, 512x redundantly.)
// ---------------------------------------------------------------------------
__global__ __launch_bounds__(256) void convert_kernel(
    const float* __restrict__ h1, const float* __restrict__ h2,
    bf16x8* __restrict__ Af, bf16x8* __restrict__ h1c,
    const float* __restrict__ w, unsigned short* __restrict__ Wf)
{
    const int tid = threadIdx.x;
    const int bid = blockIdx.x;

    if (bid < 1024) {
        const int g = bid * 256 + tid;
        const int lane = g & 63, kc = (g >> 6) & 15, mt = (g >> 10) & 127, z = g >> 17;
        const int quad = lane >> 4, l16 = lane & 15;
        const float* __restrict__ src = (z ? h2 : h1)
            + ((size_t)(mt * 16 + l16)) * E_ + kc * 32 + quad * 8;
        const float4 x0 = *(const float4*)src;
        const float4 x1 = *(const float4*)(src + 4);
        const float xs[8] = {x0.x, x0.y, x0.z, x0.w, x1.x, x1.y, x1.z, x1.w};
        bf16x8 ah, al;
#pragma unroll
        for (int j = 0; j < 8; ++j) {
            short h, l; splitT(xs[j] * KC, &h, &l);
            ah[j] = h; al[j] = l;
        }
        // A carries the KC scale (W unscaled); hi*lo cross term still ~2^-16.
        const size_t o = (((size_t)z * 256 + mt) * 16 + kc) * 64 + lane;
        Af[o] = ah;
        Af[o + (size_t)128 * 16 * 64] = al;
    } else if (bid < 1536) {
        const int s = (bid - 1024) * 256 + tid;
        const int lane = s & 63, kc = (s >> 6) & 15, et = (s >> 10) & 31, b = s >> 15;
        const int quad = lane >> 4, l16 = lane & 15;
        const float* __restrict__ src =
            h1 + ((size_t)b * S_ + kc * 32 + quad * 8) * E_ + et * 16 + l16;
        bf16x8 c;
#pragma unroll
        for (int j = 0; j < 8; ++j)
            c[j] = (short)bf16rn(src[(size_t)j * E_]);
        h1c[s] = c;
    } else {
        // ---- W -> Wf hi/lo B-frags (same mapping prep's LDS used) ----
        const int bw = bid - 1536;                       // 0..127
        const int z = bw >> 6, ngg = (bw >> 3) & 7, part = bw & 7;
        const int r8 = tid >> 5, ul = tid & 31;
        const int ntc = ul >> 4, l16c = ul & 15;
        const float* __restrict__ Wp = w + (size_t)z * E_ * U_ + ngg * 32 + ul;
#pragma unroll
        for (int it = 0; it < 8; ++it) {
            const int k = (part * 8 + it) * 8 + r8;      // 0..511
            short h, l;
            splitT(Wp[(size_t)k * U_], &h, &l);
            const int kc = k >> 5, quad = (k >> 3) & 3, jj = k & 7;
            const size_t o =
                ((((size_t)(z * 16 + ngg * 2 + ntc) * 16 + kc) * 64)
                 + (quad * 16 + l16c)) * 8 + jj;
            Wf[o] = (unsigned short)h;
            Wf[o + 262144] = (unsigned short)l;          // lo plane
        }
    }
}

// ---------------------------------------------------------------------------
// prep (512 blocks x 256 thr): pre-GEMMs, pure streaming MFMA.
//  NO LDS, NO splitT, NO barriers (R2 rebuilt W frags in LDS per block).
//  block <-> (z, ngg 0..7 = 32-u slab, mq 0..31); wave -> m-tile mt = mq*4+wv.
//  3-MFMA hi/lo per (kc, nt). Operands stream from L2/LLC (Af, Wf).
//  Epilogue exp2 (rank-1 factorization: exp2(KC(q+k)) = eq*ek):
//    z==0: ek4[b][u>>2][j][u&3] = exp2(KC*(h1[b,j,:]@w1[:,u]))
//    z==1: eqS[b][i][u]        = exp2(KC*(h2[b,i,:]@w2[:,u]+b1[u]))
// ---------------------------------------------------------------------------
__global__ __launch_bounds__(256) void prep_gemm(
    const bf16x8* __restrict__ Af, const bf16x8* __restrict__ Wf,
    const float* __restrict__ b1,
    float* __restrict__ ek4, float* __restrict__ eqS)
{
    const int tid = threadIdx.x;
    const int bid = blockIdx.x;
    const int z = bid >> 8, ngg = (bid >> 5) & 7, mq = bid & 31;

    const int wv = tid >> 6, lane = tid & 63;
    const int quad = lane >> 4, l16 = lane & 15;
    const int mt = mq * 4 + wv, m0 = mt * 16;

    const bf16x8* __restrict__ Ah =
        Af + (((size_t)z * 256 + mt) * 16) * 64 + lane;
    const bf16x8* __restrict__ Al = Ah + (size_t)128 * 16 * 64;
    const bf16x8* __restrict__ W0 =
        Wf + (((size_t)(z * 16 + ngg * 2) * 16)) * 64 + lane;     // nt=0 hi
    const bf16x8* __restrict__ W1 = W0 + (size_t)16 * 64;         // nt=1 hi
    const bf16x8* __restrict__ W0l = W0 + 32768;                  // lo plane
    const bf16x8* __restrict__ W1l = W1 + 32768;

    f32x4 acc[2];
    acc[0] = (f32x4){0.f, 0.f, 0.f, 0.f};
    acc[1] = (f32x4){0.f, 0.f, 0.f, 0.f};

    for (int kc = 0; kc < 16; ++kc) {
        const bf16x8 ah = Ah[kc * 64];
        const bf16x8 al = Al[kc * 64];
        const bf16x8 b0h = W0[kc * 64];
        const bf16x8 b0l = W0l[kc * 64];
        const bf16x8 b1h = W1[kc * 64];
        const bf16x8 b1l = W1l[kc * 64];
        acc[0] = __builtin_amdgcn_mfma_f32_16x16x32_bf16(ah, b0h, acc[0], 0, 0, 0);
        acc[0] = __builtin_amdgcn_mfma_f32_16x16x32_bf16(ah, b0l, acc[0], 0, 0, 0);
        acc[0] = __builtin_amdgcn_mfma_f32_16x16x32_bf16(al, b0h, acc[0], 0, 0, 0);
        acc[1] = __builtin_amdgcn_mfma_f32_16x16x32_bf16(ah, b1h, acc[1], 0, 0, 0);
        acc[1] = __builtin_amdgcn_mfma_f32_16x16x32_bf16(ah, b1l, acc[1], 0, 0, 0);
        acc[1] = __builtin_amdgcn_mfma_f32_16x16x32_bf16(al, b1h, acc[1], 0, 0, 0);
    }

    if (z == 0) {
        const int b = m0 >> 9;
        const int j0 = (m0 & (S_ - 1)) + quad * 4;       // C/D row = j
#pragma unroll
        for (int nt = 0; nt < 2; ++nt) {
            const int u = (ngg * 2 + nt) * 16 + l16;     // C/D col = u
            float* __restrict__ dst =
                ek4 + ((size_t)b * 64 + (u >> 2)) * 2048 + (u & 3);
#pragma unroll
            for (int r = 0; r < 4; ++r)
                dst[(size_t)(j0 + r) * 4] = EXP2F(acc[nt][r]);
        }
    } else {
        const int row = m0 + quad * 4;
#pragma unroll
        for (int nt = 0; nt < 2; ++nt) {
            const int u = (ngg * 2 + nt) * 16 + l16;
            const float bias = KC * b1[u];
#pragma unroll
            for (int r = 0; r < 4; ++r)
                eqS[(size_t)(row + r) * U_ + u] = EXP2F(acc[nt][r] + bias);
        }
    }
}

// ---------------------------------------------------------------------------
// scores + softmax -> P packed in MFMA A-frag order (bf16). (R2 verbatim)
// TI=4: 512 thr/block, thread t <-> column j = t, FOUR query rows per block.
// grid (128,4) = 512 blocks x 8 waves. One coalesced dwordx4 k-load per 4-u
// group (ek4 interleaved); G = fma(eq,ek,1) — no transcendental per element.
// a = sum_u v_u/G_u via pairwise-product tree, 1 rcp per 4 u.
// score = c - 2a (c, b2 cancel) -> p ~ exp2(-a*KC); |a*KC| <= ~52.
// ---------------------------------------------------------------------------
__device__ __forceinline__ float quadG(float G1, float G2, float G3, float G4,
                                       float4 vq, float acc) {
    const float P12 = G1 * G2, P34 = G3 * G4;
    const float n12 = fmaf(vq.y, G1, vq.x * G2);
    const float n34 = fmaf(vq.w, G3, vq.z * G4);
    const float num = fmaf(n34, P12, n12 * P34);
    return fmaf(num, RCPF(P12 * P34), acc);
}

__global__ __launch_bounds__(512) void scores_kernel(
    const float* __restrict__ ek4, const float* __restrict__ eqS,
    const float* __restrict__ v, unsigned short* __restrict__ Pp)
{
    __shared__ float ssm[8][4];
    const int i0 = blockIdx.x * 4;
    const int b = blockIdx.y;
    const int t = threadIdx.x;          // j = t
    const int wv = t >> 6;

    const float4* __restrict__ q0v = (const float4*)(eqS + ((size_t)b * S_ + i0) * U_);
    const float4* __restrict__ q1v = q0v + (U_ / 4);
    const float4* __restrict__ q2v = q0v + 2 * (U_ / 4);
    const float4* __restrict__ q3v = q0v + 3 * (U_ / 4);
    const float4* __restrict__ vv4 = (const float4*)v;
    const float4* __restrict__ kbb = (const float4*)ek4 + (size_t)b * 64 * 512 + t;

    float a0 = 0.f, a1 = 0.f, a2 = 0.f, a3 = 0.f;
#pragma unroll 4
    for (int ub = 0; ub < U_ / 4; ++ub) {
        const float4 vq = vv4[ub];                     // uniform -> SGPR
        const float4 e = kbb[(size_t)ub * 512];        // one coalesced 16B load
        const float4 q0 = q0v[ub], q1 = q1v[ub], q2 = q2v[ub], q3 = q3v[ub];
        a0 = quadG(fmaf(q0.x, e.x, 1.f), fmaf(q0.y, e.y, 1.f),
                   fmaf(q0.z, e.z, 1.f), fmaf(q0.w, e.w, 1.f), vq, a0);
        a1 = quadG(fmaf(q1.x, e.x, 1.f), fmaf(q1.y, e.y, 1.f),
                   fmaf(q1.z, e.z, 1.f), fmaf(q1.w, e.w, 1.f), vq, a1);
        a2 = quadG(fmaf(q2.x, e.x, 1.f), fmaf(q2.y, e.y, 1.f),
                   fmaf(q2.z, e.z, 1.f), fmaf(q2.w, e.w, 1.f), vq, a2);
        a3 = quadG(fmaf(q3.x, e.x, 1.f), fmaf(q3.y, e.y, 1.f),
                   fmaf(q3.z, e.z, 1.f), fmaf(q3.w, e.w, 1.f), vq, a3);
    }

    const float p0 = EXP2F(-a0 * KC);
    const float p1 = EXP2F(-a1 * KC);
    const float p2 = EXP2F(-a2 * KC);
    const float p3 = EXP2F(-a3 * KC);
    float s0 = p0, s1 = p1, s2 = p2, s3 = p3;
#pragma unroll
    for (int off = 1; off < 64; off <<= 1) {
        s0 += __shfl_xor(s0, off, 64);
        s1 += __shfl_xor(s1, off, 64);
        s2 += __shfl_xor(s2, off, 64);
        s3 += __shfl_xor(s3, off, 64);
    }
    if ((t & 63) == 0) {
        ssm[wv][0] = s0; ssm[wv][1] = s1; ssm[wv][2] = s2; ssm[wv][3] = s3;
    }
    __syncthreads();
    s0 = ssm[0][0]; s1 = ssm[0][1]; s2 = ssm[0][2]; s3 = ssm[0][3];
#pragma unroll
    for (int k = 1; k < 8; ++k) {
        s0 += ssm[k][0]; s1 += ssm[k][1]; s2 += ssm[k][2]; s3 += ssm[k][3];
    }
    const float r0 = RCPF(s0), r1 = RCPF(s1), r2 = RCPF(s2), r3 = RCPF(s3);

    // pack into A-frag order: slot = (it*16 + j/32)*64 + quad(j)*16 + (i&15),
    // halfword j&7. i0 = 4*blockIdx.x -> rows stay inside one 16-block.
    const int itile = i0 >> 4;
    const int base = (itile * 16 + (t >> 5)) * 64 + (((t >> 3) & 3) << 4);
    unsigned short* __restrict__ pb = Pp + (size_t)b * S_ * S_;
    const int io = i0 & 15, jo = t & 7;
    pb[((base + io + 0) << 3) + jo] = bf16rn(p0 * r0);
    pb[((base + io + 1) << 3) + jo] = bf16rn(p1 * r1);
    pb[((base + io + 2) << 3) + jo] = bf16rn(p2 * r2);
    pb[((base + io + 3) << 3) + jo] = bf16rn(p3 * r3);
}

// ---------------------------------------------------------------------------
// pv: out[b] = P[b] @ h1[b]; A-frags pre-packed by scores, B-frags (h1c)
// by convert. Wave-task (b, it 0..31, eg 0..15): 16 i x 32 e. (R2 verbatim)
// grid 512x256 = 2048 wave-tasks = 2 waves/SIMD.
// ---------------------------------------------------------------------------
__global__ __launch_bounds__(256) void pv_gemm(
    const unsigned short* __restrict__ Pp, const bf16x8* __restrict__ h1c,
    float* __restrict__ out)
{
    const int tid = threadIdx.x;
    const int wv = tid >> 6, lane = tid & 63;
    const int quad = lane >> 4, l16 = lane & 15;
    const int wt = blockIdx.x * 4 + wv;          // 0..2047
    const int b = wt >> 9, rem = wt & 511;
    const int it = rem >> 4, eg = rem & 15;

    const bf16x8* __restrict__ Ab =
        (const bf16x8*)(Pp + (size_t)b * S_ * S_) + (it * 16) * 64 + lane;
    const bf16x8* __restrict__ Bb =
        h1c + ((b * 32 + eg * 2) * 16) * 64 + lane;

    f32x4 acc[2];
    acc[0] = (f32x4){0.f, 0.f, 0.f, 0.f};
    acc[1] = (f32x4){0.f, 0.f, 0.f, 0.f};

    for (int kc = 0; kc < 16; ++kc) {
        const bf16x8 a8 = Ab[kc * 64];
#pragma unroll
        for (int n = 0; n < 2; ++n) {
            const bf16x8 b8 = Bb[(n * 16 + kc) * 64];
            acc[n] = __builtin_amdgcn_mfma_f32_16x16x32_bf16(a8, b8, acc[n], 0, 0, 0);
        }
    }

    const int i = it * 16 + quad * 4;
#pragma unroll
    for (int n = 0; n < 2; ++n) {
        const int e = (eg * 2 + n) * 16 + l16;
        float* __restrict__ ob = out + ((size_t)b * S_ + i) * E_ + e;
#pragma unroll
        for (int r = 0; r < 4; ++r)
            ob[(size_t)r * E_] = acc[n][r];
    }
}

extern "C" void kernel_launch(void* const* d_in, const int* in_sizes, int n_in,
                              void* d_out, int out_size, void* d_ws, size_t ws_size,
                              hipStream_t stream) {
    const float* h1 = (const float*)d_in[0];
    const float* h2 = (const float*)d_in[1];
    const float* w  = (const float*)d_in[2];
    const float* b1 = (const float*)d_in[3];
    const float* v  = (const float*)d_in[4];
    // d_in[5] = b2: cancels in softmax, unused.
    float* out = (float*)d_out;

    char* ws = (char*)d_ws;
    float* ek4 = (float*)ws;                   ws += 2u << 20;  // 2 MB
    float* eqS = (float*)ws;                   ws += 2u << 20;  // 2 MB
    unsigned short* Pp = (unsigned short*)ws;  ws += 2u << 20;  // 2 MB
    bf16x8* h1c = (bf16x8*)ws;                 ws += 2u << 20;  // 2 MB
    bf16x8* Af  = (bf16x8*)ws;                 ws += 8u << 20;  // 8 MB
    unsigned short* Wf = (unsigned short*)ws;                   // 1 MB

    convert_kernel<<<dim3(1664), dim3(256), 0, stream>>>(h1, h2, Af, h1c, w, Wf);
    prep_gemm<<<dim3(512), dim3(256), 0, stream>>>(Af, (const bf16x8*)Wf, b1, ek4, eqS);
    scores_kernel<<<dim3(S_ / 4, B_), dim3(512), 0, stream>>>(ek4, eqS, v, Pp);
    pv_gemm<<<dim3(512), dim3(256), 0, stream>>>(Pp, h1c, out);
}